// Round 18
// baseline (92.900 us; speedup 1.0000x reference)
//
#include <hip/hip_runtime.h>

#define N_NODES 100000
#define N_EDGES 1600000
#define D_IN    256
#define D_OUT   64

#define BROWS 256                              // rows per bucket
#define NBUCK ((N_NODES + BROWS - 1) / BROWS)  // 391
#define CAP   8192                             // fixed edge capacity/bucket (avg 4092, ~64 sigma)
#define EB    8192                             // edges per scatter block
#define NSB   ((N_EDGES + EB - 1) / EB)        // 196 scatter blocks
#define NGB   ((N_NODES + 127) / 128)          // 782 gemm blocks (128 rows each)
#define MAXB  8192                             // LDS edge cap per bucket (== CAP)

typedef __attribute__((ext_vector_type(8))) short short8_t;  // 8 bf16 = 4 VGPRs
typedef __attribute__((ext_vector_type(4))) float f32x4;

// f32 -> bf16 round-to-nearest-even (bit idiom; cold paths only).
static __device__ __forceinline__ unsigned short f2bf(float f) {
    unsigned u = __builtin_bit_cast(unsigned, f);
    unsigned r = u + 0x7FFFu + ((u >> 16) & 1u);
    return (unsigned short)(r >> 16);
}
static __device__ __forceinline__ float bf2f(unsigned short h) {
    return __builtin_bit_cast(float, (unsigned)h << 16);
}
// Packed f32x2 -> bf16x2 (single HW instr, hot path).
static __device__ __forceinline__ unsigned cvt_pk_bf16(float lo, float hi) {
    unsigned r;
    asm("v_cvt_pk_bf16_f32 %0, %1, %2" : "=v"(r) : "v"(lo), "v"(hi));
    return r;
}

// ---------------------------------------------------------------------------
// Kernel 0: init the 391 bucket cursors to b*CAP (must precede phase1).
// ---------------------------------------------------------------------------
__global__ __launch_bounds__(512) void init_kernel(int* __restrict__ gcursor) {
    const int i = threadIdx.x;
    if (i < NBUCK) gcursor[i] = i * CAP;
}

// ---------------------------------------------------------------------------
// Kernel 1 (FUSED phase1): gemm (bid>=196) || bucket scatter (bid<196).
// gemm role: 2-K-step-deep A double-buffer (4 loads in flight, distinct
// named dest buffers so the compiler can't collapse the pipeline —
// round-16's 1-deep version was folded back to VGPR=28 = zero pipelining).
// feat loads are nontemporal via ext-vector f32x4 (clang builtin rejects
// HIP_vector_type; round-17 compile fix).
// ---------------------------------------------------------------------------
__global__ __launch_bounds__(512, 8) void phase1_kernel(const float* __restrict__ feat,
                                                        const float* __restrict__ W,
                                                        const int*   __restrict__ rows,
                                                        const int*   __restrict__ cols,
                                                        const float* __restrict__ vals,
                                                        unsigned short* __restrict__ support,
                                                        int*  __restrict__ gcursor,
                                                        int2* __restrict__ pack) {
    __shared__ int smem[EB + 2 * NBUCK];   // 35.9 KB, shared by both roles
    const int tid = threadIdx.x;

    if (blockIdx.x < NSB) {
        // ---------------- scatter role ----------------
        int* lrows = smem;            // [EB]
        int* h     = smem + EB;       // [NBUCK]
        int* base  = h + NBUCK;       // [NBUCK]
        for (int i = tid; i < NBUCK; i += 512) h[i] = 0;
        __syncthreads();

        const int e0 = blockIdx.x * EB;
        for (int i = tid; i < EB; i += 512) {
            const int e = e0 + i;
            const int r = (e < N_EDGES) ? rows[e] : -1;
            lrows[i] = r;
            if (r >= 0) atomicAdd(&h[r >> 8], 1);
        }
        __syncthreads();

        for (int b = tid; b < NBUCK; b += 512) {
            const int c = h[b];
            base[b] = c ? atomicAdd(&gcursor[b], c) : 0;
            h[b] = 0;   // becomes local cursor
        }
        __syncthreads();

        for (int i = tid; i < EB; i += 512) {
            const int r = lrows[i];
            if (r < 0) continue;
            const int b = r >> 8;
            const int pos = base[b] + atomicAdd(&h[b], 1);
            if (pos < (b + 1) * CAP) {   // capacity guard (never triggers at this scale)
                const int e = e0 + i;
                pack[pos] = make_int2(((r & 255) << 17) | cols[e], __float_as_int(vals[e]));
            }
        }
    } else {
        // ---------------- gemm role ----------------
        const int gb = blockIdx.x - NSB;          // 0 .. NGB-1
        unsigned short* Wf = (unsigned short*)smem;   // 2048 slots x 8 bf16 = 32 KB

        #pragma unroll
        for (int i = 0; i < 4; ++i) {
            const int slot = i * 512 + tid;
            const int s  = slot >> 8;          // kstep
            const int nt = (slot >> 6) & 3;    // n-tile
            const int l  = slot & 63;          // lane it serves
            const int kbase = s * 32 + ((l >> 4) * 8);
            const int col   = nt * 16 + (l & 15);
            unsigned short tmp[8];
            #pragma unroll
            for (int e = 0; e < 8; ++e)
                tmp[e] = f2bf(W[(size_t)(kbase + e) * D_OUT + col]);
            *(short8_t*)&Wf[slot * 8] = *(short8_t*)tmp;
        }
        __syncthreads();

        const int lane = tid & 63;
        const int wave = tid >> 6;                // 0..7
        const int row0 = gb * 128 + wave * 16;    // 16 rows per wave
        if (row0 >= N_NODES) return;

        const f32x4* ap = (const f32x4*)(feat + (size_t)(row0 + (lane & 15)) * D_IN
                                              + ((lane >> 4) * 8));

        f32x4 acc[4];
        #pragma unroll
        for (int nt = 0; nt < 4; ++nt) acc[nt] = (f32x4){0.f, 0.f, 0.f, 0.f};

        // 2-deep software pipeline: steps s and s+1 prefetched; distinct
        // named buffers, statically indexed (unrolled loop -> s&1 literal).
        f32x4 bufA0 = __builtin_nontemporal_load(&ap[0]);
        f32x4 bufA1 = __builtin_nontemporal_load(&ap[1]);
        f32x4 bufB0 = __builtin_nontemporal_load(&ap[8]);
        f32x4 bufB1 = __builtin_nontemporal_load(&ap[9]);
        #pragma unroll
        for (int s = 0; s < 8; ++s) {
            f32x4 a0, a1;
            if ((s & 1) == 0) { a0 = bufA0; a1 = bufA1; }
            else              { a0 = bufB0; a1 = bufB1; }
            if (s < 6) {
                if ((s & 1) == 0) {
                    bufA0 = __builtin_nontemporal_load(&ap[(s + 2) * 8]);
                    bufA1 = __builtin_nontemporal_load(&ap[(s + 2) * 8 + 1]);
                } else {
                    bufB0 = __builtin_nontemporal_load(&ap[(s + 2) * 8]);
                    bufB1 = __builtin_nontemporal_load(&ap[(s + 2) * 8 + 1]);
                }
            }
            unsigned u[4];
            u[0] = cvt_pk_bf16(a0[0], a0[1]);
            u[1] = cvt_pk_bf16(a0[2], a0[3]);
            u[2] = cvt_pk_bf16(a1[0], a1[1]);
            u[3] = cvt_pk_bf16(a1[2], a1[3]);
            const short8_t av = *(short8_t*)u;
            #pragma unroll
            for (int nt = 0; nt < 4; ++nt) {
                const short8_t bv = *(short8_t*)&Wf[((s * 4 + nt) * 64 + lane) * 8];
                acc[nt] = __builtin_amdgcn_mfma_f32_16x16x32_bf16(av, bv, acc[nt], 0, 0, 0);
            }
        }

        #pragma unroll
        for (int nt = 0; nt < 4; ++nt) {
            #pragma unroll
            for (int reg = 0; reg < 4; ++reg) {
                const int row = row0 + (lane >> 4) * 4 + reg;
                const int col = nt * 16 + (lane & 15);
                support[(size_t)row * D_OUT + col] = f2bf(acc[nt][reg]);
            }
        }
    }
}

// ---------------------------------------------------------------------------
// Kernel 2 (FUSED sort+reduce): one 1024-thr block (16 waves) per bucket.
// (Round-16 form: LDS row-sort, edge-paired gathers, 8 in flight,
//  nontemporal out stores.)
// ---------------------------------------------------------------------------
__global__ __launch_bounds__(1024) void breduce_kernel(const int*  __restrict__ gcursor,
                                                       const int2* __restrict__ pack,
                                                       const unsigned short* __restrict__ support,
                                                       float* __restrict__ out) {
    __shared__ int2 ps[MAXB];      // 64 KB
    __shared__ int cnt[BROWS];
    __shared__ int ofs[BROWS];
    __shared__ int cur[BROWS];
    __shared__ int scn[BROWS];
    const int b     = blockIdx.x;
    const int tid   = threadIdx.x;
    const int start = b * CAP;
    int n = gcursor[b] - start;
    if (n > MAXB) n = MAXB;        // safety clamp (never triggers)
    const int lane  = tid & 63;
    const int wave  = tid >> 6;
    const int half  = lane >> 5;   // 0 or 1: which edge of a pair
    const int cl    = lane & 31;   // column-pair index (cols 2cl, 2cl+1)

    if (tid < BROWS) cnt[tid] = 0;
    __syncthreads();

    // a) histogram of local rows
    for (int i = tid; i < n; i += 1024)
        atomicAdd(&cnt[pack[start + i].x >> 17], 1);
    __syncthreads();

    // exclusive scan over 256 counters (all threads hit the barriers)
    const int v = (tid < BROWS) ? cnt[tid] : 0;
    if (tid < BROWS) scn[tid] = v;
    __syncthreads();
    #pragma unroll
    for (int off = 1; off < BROWS; off <<= 1) {
        const int t = (tid < BROWS && tid >= off) ? scn[tid - off] : 0;
        __syncthreads();
        if (tid < BROWS) scn[tid] += t;
        __syncthreads();
    }
    if (tid < BROWS) { ofs[tid] = scn[tid] - v; cur[tid] = 0; }
    __syncthreads();

    // b) row-sorted stage into LDS
    for (int i = tid; i < n; i += 1024) {
        const int2 p  = pack[start + i];
        const int  rl = p.x >> 17;
        ps[ofs[rl] + atomicAdd(&cur[rl], 1)] = p;
    }
    __syncthreads();

    // c) per-row paired reduce + ReLU
    for (int rl = wave; rl < BROWS; rl += 16) {
        const int row = b * BROWS + rl;
        if (row >= N_NODES) continue;
        const int s0 = ofs[rl];
        const int nr = cnt[rl];
        float ax0 = 0.f, ay0 = 0.f, ax1 = 0.f, ay1 = 0.f;
        float ax2 = 0.f, ay2 = 0.f, ax3 = 0.f, ay3 = 0.f;
        int k = 0;
        for (; k + 15 < nr; k += 16) {   // 16 edges via 8 paired gathers in flight
            const int2 p0 = ps[s0 + k      + half];
            const int2 p1 = ps[s0 + k + 2  + half];
            const int2 p2 = ps[s0 + k + 4  + half];
            const int2 p3 = ps[s0 + k + 6  + half];
            const int2 p4 = ps[s0 + k + 8  + half];
            const int2 p5 = ps[s0 + k + 10 + half];
            const int2 p6 = ps[s0 + k + 12 + half];
            const int2 p7 = ps[s0 + k + 14 + half];
            const unsigned q0 = *(const unsigned*)&support[(size_t)(p0.x & 0x1FFFF) * D_OUT + 2 * cl];
            const unsigned q1 = *(const unsigned*)&support[(size_t)(p1.x & 0x1FFFF) * D_OUT + 2 * cl];
            const unsigned q2 = *(const unsigned*)&support[(size_t)(p2.x & 0x1FFFF) * D_OUT + 2 * cl];
            const unsigned q3 = *(const unsigned*)&support[(size_t)(p3.x & 0x1FFFF) * D_OUT + 2 * cl];
            const unsigned q4 = *(const unsigned*)&support[(size_t)(p4.x & 0x1FFFF) * D_OUT + 2 * cl];
            const unsigned q5 = *(const unsigned*)&support[(size_t)(p5.x & 0x1FFFF) * D_OUT + 2 * cl];
            const unsigned q6 = *(const unsigned*)&support[(size_t)(p6.x & 0x1FFFF) * D_OUT + 2 * cl];
            const unsigned q7 = *(const unsigned*)&support[(size_t)(p7.x & 0x1FFFF) * D_OUT + 2 * cl];
            ax0 = fmaf(__int_as_float(p0.y), bf2f((unsigned short)(q0 & 0xFFFF)), ax0);
            ay0 = fmaf(__int_as_float(p0.y), bf2f((unsigned short)(q0 >> 16)),    ay0);
            ax1 = fmaf(__int_as_float(p1.y), bf2f((unsigned short)(q1 & 0xFFFF)), ax1);
            ay1 = fmaf(__int_as_float(p1.y), bf2f((unsigned short)(q1 >> 16)),    ay1);
            ax2 = fmaf(__int_as_float(p2.y), bf2f((unsigned short)(q2 & 0xFFFF)), ax2);
            ay2 = fmaf(__int_as_float(p2.y), bf2f((unsigned short)(q2 >> 16)),    ay2);
            ax3 = fmaf(__int_as_float(p3.y), bf2f((unsigned short)(q3 & 0xFFFF)), ax3);
            ay3 = fmaf(__int_as_float(p3.y), bf2f((unsigned short)(q3 >> 16)),    ay3);
            ax0 = fmaf(__int_as_float(p4.y), bf2f((unsigned short)(q4 & 0xFFFF)), ax0);
            ay0 = fmaf(__int_as_float(p4.y), bf2f((unsigned short)(q4 >> 16)),    ay0);
            ax1 = fmaf(__int_as_float(p5.y), bf2f((unsigned short)(q5 & 0xFFFF)), ax1);
            ay1 = fmaf(__int_as_float(p5.y), bf2f((unsigned short)(q5 >> 16)),    ay1);
            ax2 = fmaf(__int_as_float(p6.y), bf2f((unsigned short)(q6 & 0xFFFF)), ax2);
            ay2 = fmaf(__int_as_float(p6.y), bf2f((unsigned short)(q6 >> 16)),    ay2);
            ax3 = fmaf(__int_as_float(p7.y), bf2f((unsigned short)(q7 & 0xFFFF)), ax3);
            ay3 = fmaf(__int_as_float(p7.y), bf2f((unsigned short)(q7 >> 16)),    ay3);
        }
        for (; k + 7 < nr; k += 8) {   // 8 edges via 4 paired gathers
            const int2 p0 = ps[s0 + k     + half];
            const int2 p1 = ps[s0 + k + 2 + half];
            const int2 p2 = ps[s0 + k + 4 + half];
            const int2 p3 = ps[s0 + k + 6 + half];
            const unsigned q0 = *(const unsigned*)&support[(size_t)(p0.x & 0x1FFFF) * D_OUT + 2 * cl];
            const unsigned q1 = *(const unsigned*)&support[(size_t)(p1.x & 0x1FFFF) * D_OUT + 2 * cl];
            const unsigned q2 = *(const unsigned*)&support[(size_t)(p2.x & 0x1FFFF) * D_OUT + 2 * cl];
            const unsigned q3 = *(const unsigned*)&support[(size_t)(p3.x & 0x1FFFF) * D_OUT + 2 * cl];
            ax0 = fmaf(__int_as_float(p0.y), bf2f((unsigned short)(q0 & 0xFFFF)), ax0);
            ay0 = fmaf(__int_as_float(p0.y), bf2f((unsigned short)(q0 >> 16)),    ay0);
            ax1 = fmaf(__int_as_float(p1.y), bf2f((unsigned short)(q1 & 0xFFFF)), ax1);
            ay1 = fmaf(__int_as_float(p1.y), bf2f((unsigned short)(q1 >> 16)),    ay1);
            ax2 = fmaf(__int_as_float(p2.y), bf2f((unsigned short)(q2 & 0xFFFF)), ax2);
            ay2 = fmaf(__int_as_float(p2.y), bf2f((unsigned short)(q2 >> 16)),    ay2);
            ax3 = fmaf(__int_as_float(p3.y), bf2f((unsigned short)(q3 & 0xFFFF)), ax3);
            ay3 = fmaf(__int_as_float(p3.y), bf2f((unsigned short)(q3 >> 16)),    ay3);
        }
        for (; k + 1 < nr; k += 2) {   // 2 edges via 1 paired gather
            const int2 p = ps[s0 + k + half];
            const unsigned q = *(const unsigned*)&support[(size_t)(p.x & 0x1FFFF) * D_OUT + 2 * cl];
            const float vv = __int_as_float(p.y);
            ax0 = fmaf(vv, bf2f((unsigned short)(q & 0xFFFF)), ax0);
            ay0 = fmaf(vv, bf2f((unsigned short)(q >> 16)),    ay0);
        }
        if (k < nr && half == 0) {     // odd tail: low half only
            const int2 p = ps[s0 + k];
            const unsigned q = *(const unsigned*)&support[(size_t)(p.x & 0x1FFFF) * D_OUT + 2 * cl];
            const float vv = __int_as_float(p.y);
            ax0 = fmaf(vv, bf2f((unsigned short)(q & 0xFFFF)), ax0);
            ay0 = fmaf(vv, bf2f((unsigned short)(q >> 16)),    ay0);
        }
        float sx = (ax0 + ax1) + (ax2 + ax3);
        float sy = (ay0 + ay1) + (ay2 + ay3);
        sx += __shfl_xor(sx, 32, 64);
        sy += __shfl_xor(sy, 32, 64);
        if (half == 0) {
            float2 o;
            o.x = fmaxf(sx, 0.f);
            o.y = fmaxf(sy, 0.f);
            __builtin_nontemporal_store(__builtin_bit_cast(unsigned long long, o),
                (unsigned long long*)&out[(size_t)row * D_OUT + 2 * cl]);
        }
    }
}

extern "C" void kernel_launch(void* const* d_in, const int* in_sizes, int n_in,
                              void* d_out, int out_size, void* d_ws, size_t ws_size,
                              hipStream_t stream) {
    const float* feat = (const float*)d_in[0];
    const float* W    = (const float*)d_in[1];
    const int*   rows = (const int*)d_in[2];
    const int*   cols = (const int*)d_in[3];
    const float* vals = (const float*)d_in[4];
    float*       out  = (float*)d_out;

    // Workspace layout (~38.4 MB):
    unsigned short* support = (unsigned short*)d_ws;    // 6,400,000 ushort (12.8 MB)
    int*   gcursor = (int*)(support + 6400000);         // 392 ints (byte 12,800,000)
    int2*  pack    = (int2*)(gcursor + 392);            // 8B-aligned
    // pack: NBUCK * CAP = 3,203,072 int2 = 25.6 MB

    // 0) init bucket cursors
    init_kernel<<<1, 512, 0, stream>>>(gcursor);

    // 1) fused phase1: gemm (782 blocks) || bucket scatter (196 blocks)
    phase1_kernel<<<NSB + NGB, 512, 0, stream>>>(feat, W, rows, cols, vals,
                                                 support, gcursor, pack);

    // 2) fused per-bucket sort (LDS) + per-row paired register reduce + ReLU
    breduce_kernel<<<NBUCK, 1024, 0, stream>>>(gcursor, pack, support, out);
}

// Round 19
// 80.485 us; speedup vs baseline: 1.1543x; 1.1543x over previous
//
#include <hip/hip_runtime.h>

#define N_NODES 100000
#define N_EDGES 1600000
#define D_IN    256
#define D_OUT   64

#define BROWS 256                              // rows per bucket
#define NBUCK ((N_NODES + BROWS - 1) / BROWS)  // 391
#define CAP   8192                             // fixed edge capacity/bucket (avg 4092, ~64 sigma)
#define EB    8192                             // edges per scatter block
#define NSB   ((N_EDGES + EB - 1) / EB)        // 196 scatter blocks
#define NGB   ((N_NODES + 127) / 128)          // 782 gemm blocks (128 rows each)
#define MAXB  8192                             // LDS edge cap per bucket (== CAP)

typedef __attribute__((ext_vector_type(8))) short short8_t;  // 8 bf16 = 4 VGPRs
typedef __attribute__((ext_vector_type(4))) float f32x4;

// f32 -> bf16 round-to-nearest-even (bit idiom; cold paths only).
static __device__ __forceinline__ unsigned short f2bf(float f) {
    unsigned u = __builtin_bit_cast(unsigned, f);
    unsigned r = u + 0x7FFFu + ((u >> 16) & 1u);
    return (unsigned short)(r >> 16);
}
static __device__ __forceinline__ float bf2f(unsigned short h) {
    return __builtin_bit_cast(float, (unsigned)h << 16);
}
// Packed f32x2 -> bf16x2 (single HW instr, hot path).
static __device__ __forceinline__ unsigned cvt_pk_bf16(float lo, float hi) {
    unsigned r;
    asm("v_cvt_pk_bf16_f32 %0, %1, %2" : "=v"(r) : "v"(lo), "v"(hi));
    return r;
}

// ---------------------------------------------------------------------------
// Kernel 0: init the 391 bucket cursors to b*CAP (must precede phase1).
// ---------------------------------------------------------------------------
__global__ __launch_bounds__(512) void init_kernel(int* __restrict__ gcursor) {
    const int i = threadIdx.x;
    if (i < NBUCK) gcursor[i] = i * CAP;
}

// ---------------------------------------------------------------------------
// Kernel 1 (FUSED phase1): gemm (bid>=196) || bucket scatter (bid<196).
// (Round-16 proven form, 80.5 us total. Deeper source-level pipelining was
//  tried twice — compiler collapses it to VGPR=28 either way, and
//  nontemporal feat loads regress by de-merging L2 segments. Kept simple.)
// ---------------------------------------------------------------------------
__global__ __launch_bounds__(512, 8) void phase1_kernel(const float* __restrict__ feat,
                                                        const float* __restrict__ W,
                                                        const int*   __restrict__ rows,
                                                        const int*   __restrict__ cols,
                                                        const float* __restrict__ vals,
                                                        unsigned short* __restrict__ support,
                                                        int*  __restrict__ gcursor,
                                                        int2* __restrict__ pack) {
    __shared__ int smem[EB + 2 * NBUCK];   // 35.9 KB, shared by both roles
    const int tid = threadIdx.x;

    if (blockIdx.x < NSB) {
        // ---------------- scatter role ----------------
        int* lrows = smem;            // [EB]
        int* h     = smem + EB;       // [NBUCK]
        int* base  = h + NBUCK;       // [NBUCK]
        for (int i = tid; i < NBUCK; i += 512) h[i] = 0;
        __syncthreads();

        const int e0 = blockIdx.x * EB;
        for (int i = tid; i < EB; i += 512) {
            const int e = e0 + i;
            const int r = (e < N_EDGES) ? rows[e] : -1;
            lrows[i] = r;
            if (r >= 0) atomicAdd(&h[r >> 8], 1);
        }
        __syncthreads();

        for (int b = tid; b < NBUCK; b += 512) {
            const int c = h[b];
            base[b] = c ? atomicAdd(&gcursor[b], c) : 0;
            h[b] = 0;   // becomes local cursor
        }
        __syncthreads();

        for (int i = tid; i < EB; i += 512) {
            const int r = lrows[i];
            if (r < 0) continue;
            const int b = r >> 8;
            const int pos = base[b] + atomicAdd(&h[b], 1);
            if (pos < (b + 1) * CAP) {   // capacity guard (never triggers at this scale)
                const int e = e0 + i;
                pack[pos] = make_int2(((r & 255) << 17) | cols[e], __float_as_int(vals[e]));
            }
        }
    } else {
        // ---------------- gemm role ----------------
        const int gb = blockIdx.x - NSB;          // 0 .. NGB-1
        unsigned short* Wf = (unsigned short*)smem;   // 2048 slots x 8 bf16 = 32 KB

        #pragma unroll
        for (int i = 0; i < 4; ++i) {
            const int slot = i * 512 + tid;
            const int s  = slot >> 8;          // kstep
            const int nt = (slot >> 6) & 3;    // n-tile
            const int l  = slot & 63;          // lane it serves
            const int kbase = s * 32 + ((l >> 4) * 8);
            const int col   = nt * 16 + (l & 15);
            unsigned short tmp[8];
            #pragma unroll
            for (int e = 0; e < 8; ++e)
                tmp[e] = f2bf(W[(size_t)(kbase + e) * D_OUT + col]);
            *(short8_t*)&Wf[slot * 8] = *(short8_t*)tmp;
        }
        __syncthreads();

        const int lane = tid & 63;
        const int wave = tid >> 6;                // 0..7
        const int row0 = gb * 128 + wave * 16;    // 16 rows per wave
        if (row0 >= N_NODES) return;

        const float4* ap = (const float4*)(feat + (size_t)(row0 + (lane & 15)) * D_IN
                                                + ((lane >> 4) * 8));

        f32x4 acc[4];
        #pragma unroll
        for (int nt = 0; nt < 4; ++nt) acc[nt] = (f32x4){0.f, 0.f, 0.f, 0.f};

        // Software-pipelined A loads: next K-step's tile issued before the
        // current step's convert+MFMA chain.
        float4 na0 = ap[0];
        float4 na1 = ap[1];
        #pragma unroll
        for (int s = 0; s < 8; ++s) {
            const float4 a0 = na0;
            const float4 a1 = na1;
            if (s < 7) {
                na0 = ap[(s + 1) * 8];
                na1 = ap[(s + 1) * 8 + 1];
            }
            unsigned u[4];
            u[0] = cvt_pk_bf16(a0.x, a0.y);
            u[1] = cvt_pk_bf16(a0.z, a0.w);
            u[2] = cvt_pk_bf16(a1.x, a1.y);
            u[3] = cvt_pk_bf16(a1.z, a1.w);
            const short8_t av = *(short8_t*)u;
            #pragma unroll
            for (int nt = 0; nt < 4; ++nt) {
                const short8_t bv = *(short8_t*)&Wf[((s * 4 + nt) * 64 + lane) * 8];
                acc[nt] = __builtin_amdgcn_mfma_f32_16x16x32_bf16(av, bv, acc[nt], 0, 0, 0);
            }
        }

        #pragma unroll
        for (int nt = 0; nt < 4; ++nt) {
            #pragma unroll
            for (int reg = 0; reg < 4; ++reg) {
                const int row = row0 + (lane >> 4) * 4 + reg;
                const int col = nt * 16 + (lane & 15);
                support[(size_t)row * D_OUT + col] = f2bf(acc[nt][reg]);
            }
        }
    }
}

// ---------------------------------------------------------------------------
// Kernel 2 (FUSED sort+reduce): one 1024-thr block (16 waves) per bucket.
//   a) 256-counter LDS histogram + scan of local rows (int atomics)
//   b) scatter the bucket's edges ROW-SORTED into LDS ps[] (int2, 64 KB)
//   c) per-row reduce, EDGE-PAIRED (half = lane>>5 picks edge of a pair,
//      cl = lane&31 picks a uint = 2 bf16 cols); main loop keeps 8 gathers
//      in flight (16 edges/iter). Halves combined via shfl_xor(32);
//      lanes 0-31 write float2 + ReLU nontemporally.
// LDS 68 KB -> 2 blocks/CU -> 32 waves/CU.
// ---------------------------------------------------------------------------
__global__ __launch_bounds__(1024) void breduce_kernel(const int*  __restrict__ gcursor,
                                                       const int2* __restrict__ pack,
                                                       const unsigned short* __restrict__ support,
                                                       float* __restrict__ out) {
    __shared__ int2 ps[MAXB];      // 64 KB
    __shared__ int cnt[BROWS];
    __shared__ int ofs[BROWS];
    __shared__ int cur[BROWS];
    __shared__ int scn[BROWS];
    const int b     = blockIdx.x;
    const int tid   = threadIdx.x;
    const int start = b * CAP;
    int n = gcursor[b] - start;
    if (n > MAXB) n = MAXB;        // safety clamp (never triggers)
    const int lane  = tid & 63;
    const int wave  = tid >> 6;
    const int half  = lane >> 5;   // 0 or 1: which edge of a pair
    const int cl    = lane & 31;   // column-pair index (cols 2cl, 2cl+1)

    if (tid < BROWS) cnt[tid] = 0;
    __syncthreads();

    // a) histogram of local rows
    for (int i = tid; i < n; i += 1024)
        atomicAdd(&cnt[pack[start + i].x >> 17], 1);
    __syncthreads();

    // exclusive scan over 256 counters (all threads hit the barriers)
    const int v = (tid < BROWS) ? cnt[tid] : 0;
    if (tid < BROWS) scn[tid] = v;
    __syncthreads();
    #pragma unroll
    for (int off = 1; off < BROWS; off <<= 1) {
        const int t = (tid < BROWS && tid >= off) ? scn[tid - off] : 0;
        __syncthreads();
        if (tid < BROWS) scn[tid] += t;
        __syncthreads();
    }
    if (tid < BROWS) { ofs[tid] = scn[tid] - v; cur[tid] = 0; }
    __syncthreads();

    // b) row-sorted stage into LDS
    for (int i = tid; i < n; i += 1024) {
        const int2 p  = pack[start + i];
        const int  rl = p.x >> 17;
        ps[ofs[rl] + atomicAdd(&cur[rl], 1)] = p;
    }
    __syncthreads();

    // c) per-row paired reduce + ReLU
    for (int rl = wave; rl < BROWS; rl += 16) {
        const int row = b * BROWS + rl;
        if (row >= N_NODES) continue;
        const int s0 = ofs[rl];
        const int nr = cnt[rl];
        float ax0 = 0.f, ay0 = 0.f, ax1 = 0.f, ay1 = 0.f;
        float ax2 = 0.f, ay2 = 0.f, ax3 = 0.f, ay3 = 0.f;
        int k = 0;
        for (; k + 15 < nr; k += 16) {   // 16 edges via 8 paired gathers in flight
            const int2 p0 = ps[s0 + k      + half];
            const int2 p1 = ps[s0 + k + 2  + half];
            const int2 p2 = ps[s0 + k + 4  + half];
            const int2 p3 = ps[s0 + k + 6  + half];
            const int2 p4 = ps[s0 + k + 8  + half];
            const int2 p5 = ps[s0 + k + 10 + half];
            const int2 p6 = ps[s0 + k + 12 + half];
            const int2 p7 = ps[s0 + k + 14 + half];
            const unsigned q0 = *(const unsigned*)&support[(size_t)(p0.x & 0x1FFFF) * D_OUT + 2 * cl];
            const unsigned q1 = *(const unsigned*)&support[(size_t)(p1.x & 0x1FFFF) * D_OUT + 2 * cl];
            const unsigned q2 = *(const unsigned*)&support[(size_t)(p2.x & 0x1FFFF) * D_OUT + 2 * cl];
            const unsigned q3 = *(const unsigned*)&support[(size_t)(p3.x & 0x1FFFF) * D_OUT + 2 * cl];
            const unsigned q4 = *(const unsigned*)&support[(size_t)(p4.x & 0x1FFFF) * D_OUT + 2 * cl];
            const unsigned q5 = *(const unsigned*)&support[(size_t)(p5.x & 0x1FFFF) * D_OUT + 2 * cl];
            const unsigned q6 = *(const unsigned*)&support[(size_t)(p6.x & 0x1FFFF) * D_OUT + 2 * cl];
            const unsigned q7 = *(const unsigned*)&support[(size_t)(p7.x & 0x1FFFF) * D_OUT + 2 * cl];
            ax0 = fmaf(__int_as_float(p0.y), bf2f((unsigned short)(q0 & 0xFFFF)), ax0);
            ay0 = fmaf(__int_as_float(p0.y), bf2f((unsigned short)(q0 >> 16)),    ay0);
            ax1 = fmaf(__int_as_float(p1.y), bf2f((unsigned short)(q1 & 0xFFFF)), ax1);
            ay1 = fmaf(__int_as_float(p1.y), bf2f((unsigned short)(q1 >> 16)),    ay1);
            ax2 = fmaf(__int_as_float(p2.y), bf2f((unsigned short)(q2 & 0xFFFF)), ax2);
            ay2 = fmaf(__int_as_float(p2.y), bf2f((unsigned short)(q2 >> 16)),    ay2);
            ax3 = fmaf(__int_as_float(p3.y), bf2f((unsigned short)(q3 & 0xFFFF)), ax3);
            ay3 = fmaf(__int_as_float(p3.y), bf2f((unsigned short)(q3 >> 16)),    ay3);
            ax0 = fmaf(__int_as_float(p4.y), bf2f((unsigned short)(q4 & 0xFFFF)), ax0);
            ay0 = fmaf(__int_as_float(p4.y), bf2f((unsigned short)(q4 >> 16)),    ay0);
            ax1 = fmaf(__int_as_float(p5.y), bf2f((unsigned short)(q5 & 0xFFFF)), ax1);
            ay1 = fmaf(__int_as_float(p5.y), bf2f((unsigned short)(q5 >> 16)),    ay1);
            ax2 = fmaf(__int_as_float(p6.y), bf2f((unsigned short)(q6 & 0xFFFF)), ax2);
            ay2 = fmaf(__int_as_float(p6.y), bf2f((unsigned short)(q6 >> 16)),    ay2);
            ax3 = fmaf(__int_as_float(p7.y), bf2f((unsigned short)(q7 & 0xFFFF)), ax3);
            ay3 = fmaf(__int_as_float(p7.y), bf2f((unsigned short)(q7 >> 16)),    ay3);
        }
        for (; k + 7 < nr; k += 8) {   // 8 edges via 4 paired gathers
            const int2 p0 = ps[s0 + k     + half];
            const int2 p1 = ps[s0 + k + 2 + half];
            const int2 p2 = ps[s0 + k + 4 + half];
            const int2 p3 = ps[s0 + k + 6 + half];
            const unsigned q0 = *(const unsigned*)&support[(size_t)(p0.x & 0x1FFFF) * D_OUT + 2 * cl];
            const unsigned q1 = *(const unsigned*)&support[(size_t)(p1.x & 0x1FFFF) * D_OUT + 2 * cl];
            const unsigned q2 = *(const unsigned*)&support[(size_t)(p2.x & 0x1FFFF) * D_OUT + 2 * cl];
            const unsigned q3 = *(const unsigned*)&support[(size_t)(p3.x & 0x1FFFF) * D_OUT + 2 * cl];
            ax0 = fmaf(__int_as_float(p0.y), bf2f((unsigned short)(q0 & 0xFFFF)), ax0);
            ay0 = fmaf(__int_as_float(p0.y), bf2f((unsigned short)(q0 >> 16)),    ay0);
            ax1 = fmaf(__int_as_float(p1.y), bf2f((unsigned short)(q1 & 0xFFFF)), ax1);
            ay1 = fmaf(__int_as_float(p1.y), bf2f((unsigned short)(q1 >> 16)),    ay1);
            ax2 = fmaf(__int_as_float(p2.y), bf2f((unsigned short)(q2 & 0xFFFF)), ax2);
            ay2 = fmaf(__int_as_float(p2.y), bf2f((unsigned short)(q2 >> 16)),    ay2);
            ax3 = fmaf(__int_as_float(p3.y), bf2f((unsigned short)(q3 & 0xFFFF)), ax3);
            ay3 = fmaf(__int_as_float(p3.y), bf2f((unsigned short)(q3 >> 16)),    ay3);
        }
        for (; k + 1 < nr; k += 2) {   // 2 edges via 1 paired gather
            const int2 p = ps[s0 + k + half];
            const unsigned q = *(const unsigned*)&support[(size_t)(p.x & 0x1FFFF) * D_OUT + 2 * cl];
            const float vv = __int_as_float(p.y);
            ax0 = fmaf(vv, bf2f((unsigned short)(q & 0xFFFF)), ax0);
            ay0 = fmaf(vv, bf2f((unsigned short)(q >> 16)),    ay0);
        }
        if (k < nr && half == 0) {     // odd tail: low half only
            const int2 p = ps[s0 + k];
            const unsigned q = *(const unsigned*)&support[(size_t)(p.x & 0x1FFFF) * D_OUT + 2 * cl];
            const float vv = __int_as_float(p.y);
            ax0 = fmaf(vv, bf2f((unsigned short)(q & 0xFFFF)), ax0);
            ay0 = fmaf(vv, bf2f((unsigned short)(q >> 16)),    ay0);
        }
        float sx = (ax0 + ax1) + (ax2 + ax3);
        float sy = (ay0 + ay1) + (ay2 + ay3);
        sx += __shfl_xor(sx, 32, 64);
        sy += __shfl_xor(sy, 32, 64);
        if (half == 0) {
            float2 o;
            o.x = fmaxf(sx, 0.f);
            o.y = fmaxf(sy, 0.f);
            __builtin_nontemporal_store(__builtin_bit_cast(unsigned long long, o),
                (unsigned long long*)&out[(size_t)row * D_OUT + 2 * cl]);
        }
    }
}

extern "C" void kernel_launch(void* const* d_in, const int* in_sizes, int n_in,
                              void* d_out, int out_size, void* d_ws, size_t ws_size,
                              hipStream_t stream) {
    const float* feat = (const float*)d_in[0];
    const float* W    = (const float*)d_in[1];
    const int*   rows = (const int*)d_in[2];
    const int*   cols = (const int*)d_in[3];
    const float* vals = (const float*)d_in[4];
    float*       out  = (float*)d_out;

    // Workspace layout (~38.4 MB):
    unsigned short* support = (unsigned short*)d_ws;    // 6,400,000 ushort (12.8 MB)
    int*   gcursor = (int*)(support + 6400000);         // 392 ints (byte 12,800,000)
    int2*  pack    = (int2*)(gcursor + 392);            // 8B-aligned
    // pack: NBUCK * CAP = 3,203,072 int2 = 25.6 MB

    // 0) init bucket cursors
    init_kernel<<<1, 512, 0, stream>>>(gcursor);

    // 1) fused phase1: gemm (782 blocks) || bucket scatter (196 blocks)
    phase1_kernel<<<NSB + NGB, 512, 0, stream>>>(feat, W, rows, cols, vals,
                                                 support, gcursor, pack);

    // 2) fused per-bucket sort (LDS) + per-row paired register reduce + ReLU
    breduce_kernel<<<NBUCK, 1024, 0, stream>>>(gcursor, pack, support, out);
}